// Round 8
// baseline (1509.064 us; speedup 1.0000x reference)
//
#include <hip/hip_runtime.h>
#include <stdint.h>

typedef unsigned long long u64;

#define NR   8192
#define INC  512
#define HID  256
#define OUTC 64
#define NW   128          // 8192 / 64 bitmap words per row
#define BN_EPS 1e-5f
#define NZBUF 1152        // max nnz per decode call (worst-case ~800; >12 sigma margin)

// ---------------- workspace layout ----------------
static constexpr size_t OFF_H    = 0;                               // [NR][HID]   f32  8 MB
static constexpr size_t OFF_Z    = OFF_H    + (size_t)NR*HID*4;     // [NR][2HID]  f32 16 MB
static constexpr size_t OFF_PQ   = OFF_Z    + (size_t)NR*2*HID*4;   // [NR][128]   f32  4 MB
static constexpr size_t OFF_BMP  = OFF_PQ   + (size_t)NR*128*4;     // [2][NR][NW] u64 16 MB
static constexpr size_t OFF_DIS  = OFF_BMP  + (size_t)2*NR*NW*8;    // [2][NR] f32
static constexpr size_t OFF_SUM  = OFF_DIS  + (size_t)2*NR*4;
static constexpr size_t OFF_SSQ  = OFF_SUM  + (size_t)2*HID*4;
static constexpr size_t WS_NEED  = OFF_SSQ  + (size_t)2*HID*4;      // ~44 MB

// ---------------------------------------------------------------------------
// 1. Bitmap extraction + row norm: grid (NR, 2) — y selects matrix. One block
//    per row, ballot over 4 waves. Support + row count fully determine the
//    normalized adjacency (value = dis[r]*dis[c] on support).
//    dis[r] = 1/sqrt(rownnz) computed here directly.
__global__ void extract_bitmap(const float* __restrict__ A, const float* __restrict__ A2,
                               u64* __restrict__ words, float* __restrict__ dis) {
    const int r    = blockIdx.x;
    const int mat  = blockIdx.y;
    const int tid  = threadIdx.x;
    const int lane = tid & 63;
    const int wv   = tid >> 6;             // 4 waves
    __shared__ int scnt;
    if (tid == 0) scnt = 0;
    __syncthreads();
    const float* rowp = (mat ? A2 : A) + (size_t)r * NR;
    u64* wout = words + ((size_t)mat * NR + r) * NW;
    int myc = 0;
    for (int w = wv; w < NW; w += 4) {
        float v = rowp[w * 64 + lane];     // 256B coalesced per wave
        u64 m = __ballot(v != 0.0f);
        if (lane == 0) {
            wout[w] = m;
            myc += __popcll(m);
        }
    }
    if (lane == 0) atomicAdd(&scnt, myc);
    __syncthreads();
    if (tid == 0) {
        int c = scnt;
        dis[mat * NR + r] = (c > 0) ? (float)(1.0 / sqrt((double)c)) : 0.0f;
    }
}

// ---------------------------------------------------------------------------
// 2. Embed GEMM: h = relu(x @ w_embed^T + b)   M=8192 K=512 N=256, fp32 VALU
__global__ void gemm_embed(const float* __restrict__ X, const float* __restrict__ W,
                           const float* __restrict__ B, float* __restrict__ H) {
    __shared__ __align__(16) float sA[16][68];
    __shared__ __align__(16) float sB[16][68];
    const int m0 = blockIdx.x * 64, n0 = blockIdx.y * 64;
    const int tid = threadIdx.x;
    const int tx = tid & 15, ty = tid >> 4;
    float acc[4][4] = {};
    for (int kt = 0; kt < INC; kt += 16) {
        for (int e = tid; e < 64 * 16; e += 256) {
            int row = e >> 4, k = e & 15;
            sA[k][row] = X[(size_t)(m0 + row) * INC + kt + k];
            sB[k][row] = W[(size_t)(n0 + row) * INC + kt + k];
        }
        __syncthreads();
#pragma unroll
        for (int k = 0; k < 16; ++k) {
            float4 av = *(const float4*)&sA[k][ty * 4];
            float4 bv = *(const float4*)&sB[k][tx * 4];
            float a[4] = {av.x, av.y, av.z, av.w};
            float b[4] = {bv.x, bv.y, bv.z, bv.w};
#pragma unroll
            for (int i = 0; i < 4; ++i)
#pragma unroll
                for (int j = 0; j < 4; ++j) acc[i][j] = fmaf(a[i], b[j], acc[i][j]);
        }
        __syncthreads();
    }
#pragma unroll
    for (int i = 0; i < 4; ++i)
#pragma unroll
        for (int j = 0; j < 4; ++j) {
            int m = m0 + ty * 4 + i, n = n0 + tx * 4 + j;
            H[(size_t)m * HID + n] = fmaxf(acc[i][j] + B[n], 0.0f);
        }
}

// ---------------------------------------------------------------------------
// 3. conv1 SpMM via bitmap decode. Block = one output row, 128 threads
//    (thread j owns 2 consecutive cols -> float2 gather). Per column-phase:
//    decode set bits into packed LDS (col,valbits) records, then counted
//    gather. Phasing keeps the gathered src slice ~2MB (L2-resident).
template <int WSRC, int VEC>
__device__ void spmm_phase(const u64* __restrict__ wp, int w0, int nw,
                           const float* __restrict__ disc, const float* __restrict__ src,
                           int j, uint2* s_nz, int* s_off, float* acc) {
    const int tid = threadIdx.x;
    __syncthreads();                       // protect shared reuse across phases
    u64 m = 0;
    if (tid < nw) {
        m = wp[w0 + tid];
        s_off[tid] = __popcll(m);
    }
    __syncthreads();
    if (tid < 64) {                        // exclusive scan over <=64 word counts
        int cnt_i = (tid < nw) ? s_off[tid] : 0;
        int v = cnt_i;
#pragma unroll
        for (int d = 1; d < 64; d <<= 1) {
            int t = __shfl_up(v, d, 64);
            if (tid >= d) v += t;
        }
        if (tid < nw) s_off[tid] = v - cnt_i;
        if (tid == 63) s_off[64] = v;      // total
    }
    __syncthreads();
    const int total = s_off[64];
    if (tid < nw) {
        int o = s_off[tid];
        u64 mm = m;
        while (mm) {
            int b = __builtin_ctzll(mm);
            mm &= mm - 1;
            int c = (w0 + tid) * 64 + b;
            s_nz[o] = make_uint2((unsigned)c, __float_as_uint(disc[c]));
            ++o;
        }
    }
    __syncthreads();
#pragma unroll 4
    for (int k = 0; k < total; ++k) {
        uint2 p = s_nz[k];                 // ds_read_b64 broadcast
        float val = __uint_as_float(p.y);
        const float* sp = &src[(size_t)p.x * WSRC + VEC * j];
        if constexpr (VEC == 2) {
            float2 v = *(const float2*)sp;
            acc[0] = fmaf(val, v.x, acc[0]);
            acc[1] = fmaf(val, v.y, acc[1]);
        } else {
            float4 v = *(const float4*)sp;
            acc[0] = fmaf(val, v.x, acc[0]);
            acc[1] = fmaf(val, v.y, acc[1]);
            acc[2] = fmaf(val, v.z, acc[2]);
            acc[3] = fmaf(val, v.w, acc[3]);
        }
    }
}

template <int WSRC, int VEC, int NPHASE>
__global__ __launch_bounds__(128, 8)   // pin VGPR<=64: keep 32 waves/CU
void spmm_kernel(const u64* __restrict__ bmp, const float* __restrict__ dis,
                 const float* __restrict__ src, float* __restrict__ dst) {
    const int r = blockIdx.x;
    const int j = threadIdx.x;             // blockDim.x == WSRC/VEC == 128
    __shared__ uint2 s_nz[NZBUF];
    __shared__ int s_off[65];
    const u64* wpA = bmp + (size_t)r * NW;
    const u64* wpB = bmp + (size_t)(NR + r) * NW;
    const float* disA = dis;
    const float* disB = dis + NR;
    float accA[VEC] = {}, accB[VEC] = {};
    const int WPP = NW / NPHASE;
    for (int ph = 0; ph < NPHASE; ++ph) {
        int w0 = ph * WPP;
        spmm_phase<WSRC, VEC>(wpA, w0, WPP, disA, src, j, s_nz, s_off, accA);
        spmm_phase<WSRC, VEC>(wpB, w0, WPP, disB, src, j, s_nz, s_off, accB);
    }
    const float da = disA[r], db = disB[r];
#pragma unroll
    for (int q = 0; q < VEC; ++q) {
        dst[(size_t)r * 2 * WSRC + VEC * j + q]        = da * accA[q];
        dst[(size_t)r * 2 * WSRC + WSRC + VEC * j + q] = db * accB[q];
    }
}

// ---------------------------------------------------------------------------
// 4. BatchNorm (batch statistics over 8192 rows, per column of z[NR][512])
__global__ void zero_stats(float* __restrict__ gsum, float* __restrict__ gssq) {
    int i = blockIdx.x * 256 + threadIdx.x;
    if (i < 2 * HID) gsum[i] = 0.0f;
    else if (i < 4 * HID) gssq[i - 2 * HID] = 0.0f;
}

__global__ void bn_stats(const float* __restrict__ Z, float* __restrict__ gsum,
                         float* __restrict__ gssq) {
    // grid (8, 64): 8 col-groups of 64, 64 row-chunks of 128. block 256 = 64 cols x 4
    const int tid = threadIdx.x;
    const int cl = tid & 63, rg = tid >> 6;
    const int c = blockIdx.x * 64 + cl;
    const int r0 = blockIdx.y * 128 + rg * 32;
    float s = 0.0f, s2 = 0.0f;
    for (int i = 0; i < 32; ++i) {
        float v = Z[(size_t)(r0 + i) * (2 * HID) + c];
        s += v;
        s2 += v * v;
    }
    __shared__ float red[2][4][64];
    red[0][rg][cl] = s;
    red[1][rg][cl] = s2;
    __syncthreads();
    if (tid < 64) {
        float t0 = red[0][0][tid] + red[0][1][tid] + red[0][2][tid] + red[0][3][tid];
        float t1 = red[1][0][tid] + red[1][1][tid] + red[1][2][tid] + red[1][3][tid];
        atomicAdd(&gsum[blockIdx.x * 64 + tid], t0);
        atomicAdd(&gssq[blockIdx.x * 64 + tid], t1);
    }
}

__global__ void bn_apply(float* __restrict__ Z, const float* __restrict__ gsum,
                         const float* __restrict__ gssq, const float* __restrict__ gamma,
                         const float* __restrict__ beta) {
    const size_t idx = (size_t)blockIdx.x * 256 + threadIdx.x;   // < NR*512
    const int c = (int)(idx & (2 * HID - 1));
    const float inv = 1.0f / (float)NR;
    float mean = gsum[c] * inv;
    float var = fmaxf(gssq[c] * inv - mean * mean, 0.0f);
    float rs = rsqrtf(var + BN_EPS);
    Z[idx] = (Z[idx] - mean) * rs * gamma[c] + beta[c];
}

// ---------------------------------------------------------------------------
// 5. PQ GEMM: PQ[r][n] = z[r] . WF[n][768+k]  (n<64, "P")
//             PQ[r][n] = z[r] . WF[n-64][1280+k] (n>=64, "Q")
//    M=8192 K=512 N=128; 32x128 tile, 256 threads -> 256 blocks.
//    (Factorization: (A@z)@W3a^T = A@(z@W3a^T), same for A2/W3b.)
__global__ void gemm_pq(const float* __restrict__ Z, const float* __restrict__ WF,
                        float* __restrict__ PQ) {
    __shared__ __align__(16) float sA[16][36];
    __shared__ __align__(16) float sB[16][132];
    const int m0 = blockIdx.x * 32;
    const int tid = threadIdx.x;
    const int tx = tid & 31, ty = tid >> 5;   // tx: 32x4 = 128 cols, ty: 8x4 = 32 rows
    float acc[4][4] = {};
    for (int kt = 0; kt < 2 * HID; kt += 16) {
        for (int e = tid; e < 32 * 16; e += 256) {
            int row = e >> 4, k = e & 15;
            sA[k][row] = Z[(size_t)(m0 + row) * (2 * HID) + kt + k];
        }
        for (int e = tid; e < 128 * 16; e += 256) {
            int n = e >> 4, k = e & 15;
            int col = (n < 64) ? (3 * HID + kt + k) : (5 * HID + kt + k);
            sB[k][n] = WF[(size_t)(n & 63) * (7 * HID) + col];
        }
        __syncthreads();
#pragma unroll
        for (int k = 0; k < 16; ++k) {
            float4 av = *(const float4*)&sA[k][ty * 4];
            float4 bv = *(const float4*)&sB[k][tx * 4];
            float a[4] = {av.x, av.y, av.z, av.w};
            float b[4] = {bv.x, bv.y, bv.z, bv.w};
#pragma unroll
            for (int i = 0; i < 4; ++i)
#pragma unroll
                for (int j = 0; j < 4; ++j) acc[i][j] = fmaf(a[i], b[j], acc[i][j]);
        }
        __syncthreads();
    }
#pragma unroll
    for (int i = 0; i < 4; ++i)
#pragma unroll
        for (int j = 0; j < 4; ++j) {
            int m = m0 + ty * 4 + i, n = tx * 4 + j;
            PQ[(size_t)m * 128 + n] = acc[i][j];
        }
}

// ---------------------------------------------------------------------------
// 6. Final GEMM (h,z parts only; K=768): out = h@W1^T + z@W2^T + b
//    32x64 tile, 128 thr -> 256 blocks. spmm_pq adds the z2 contribution after.
__global__ void gemm_final(const float* __restrict__ H, const float* __restrict__ Z,
                           const float* __restrict__ WF, const float* __restrict__ B,
                           float* __restrict__ OUT) {
    __shared__ __align__(16) float sA[16][36];
    __shared__ __align__(16) float sB[16][68];
    const int m0 = blockIdx.x * 32;
    const int tid = threadIdx.x;
    const int tx = tid & 15, ty = tid >> 4;   // tx: 16x4 = 64 cols, ty: 8x4 = 32 rows
    float acc[4][4] = {};
    for (int kt = 0; kt < 3 * HID; kt += 16) {
        const float* src;
        int stride, koff;
        if (kt < HID) { src = H; stride = HID;     koff = kt; }
        else          { src = Z; stride = 2 * HID; koff = kt - HID; }
        for (int e = tid; e < 32 * 16; e += 128) {
            int row = e >> 4, k = e & 15;
            sA[k][row] = src[(size_t)(m0 + row) * stride + koff + k];
        }
        for (int e = tid; e < 64 * 16; e += 128) {
            int row = e >> 4, k = e & 15;
            sB[k][row] = WF[(size_t)row * (7 * HID) + kt + k];   // row<64 = out ch
        }
        __syncthreads();
#pragma unroll
        for (int k = 0; k < 16; ++k) {
            float4 av = *(const float4*)&sA[k][ty * 4];
            float4 bv = *(const float4*)&sB[k][tx * 4];
            float a[4] = {av.x, av.y, av.z, av.w};
            float b[4] = {bv.x, bv.y, bv.z, bv.w};
#pragma unroll
            for (int i = 0; i < 4; ++i)
#pragma unroll
                for (int j = 0; j < 4; ++j) acc[i][j] = fmaf(a[i], b[j], acc[i][j]);
        }
        __syncthreads();
    }
#pragma unroll
    for (int i = 0; i < 4; ++i)
#pragma unroll
        for (int j = 0; j < 4; ++j) {
            int m = m0 + ty * 4 + i, n = tx * 4 + j;
            OUT[(size_t)m * OUTC + n] = acc[i][j] + B[n];
        }
}

// ---------------------------------------------------------------------------
// 7. conv2' SpMM: out[r][j] += disA[r]*sum_{c in A(r)} disA[c]*P[c][j]
//                            + disB[r]*sum_{c in A2(r)} disB[c]*Q[c][j]
//    PQ is 4MB (L2-resident). Block = row, 128 threads = 2 waves.
//    2 word-phases; per phase decode A then A2 edge lists, then gather:
//    wave0 = all A edges + first half of A2; wave1 = second half of A2.
__device__ int decode64(const u64* __restrict__ wp, int w0,
                        const float* __restrict__ disc, uint2* s_nz, int* s_off) {
    const int tid = threadIdx.x;
    u64 m = 0;
    if (tid < 64) {
        m = wp[w0 + tid];
        s_off[tid] = __popcll(m);
    }
    __syncthreads();
    if (tid < 64) {
        int cnt_i = s_off[tid];
        int v = cnt_i;
#pragma unroll
        for (int d = 1; d < 64; d <<= 1) {
            int t = __shfl_up(v, d, 64);
            if (tid >= d) v += t;
        }
        s_off[tid] = v - cnt_i;
        if (tid == 63) s_off[64] = v;
    }
    __syncthreads();
    int total = s_off[64];
    if (tid < 64) {
        int o = s_off[tid];
        u64 mm = m;
        while (mm) {
            int b = __builtin_ctzll(mm);
            mm &= mm - 1;
            int c = (w0 + tid) * 64 + b;
            s_nz[o] = make_uint2((unsigned)c, __float_as_uint(disc[c]));
            ++o;
        }
    }
    __syncthreads();
    return total;
}

__global__ __launch_bounds__(128, 8)
void spmm_pq(const u64* __restrict__ bmp, const float* __restrict__ dis,
             const float* __restrict__ PQ, float* __restrict__ OUT) {
    const int r = blockIdx.x;
    const int tid = threadIdx.x;
    const int j = tid & 63, half = tid >> 6;
    __shared__ uint2 s_nzA[128];
    __shared__ uint2 s_nzB[NZBUF];
    __shared__ int s_off[65];
    __shared__ float s_res[128];
    const u64* wpA = bmp + (size_t)r * NW;
    const u64* wpB = bmp + (size_t)(NR + r) * NW;
    const float* disA = dis;
    const float* disB = dis + NR;
    float accA = 0.0f, accB = 0.0f;
    for (int ph = 0; ph < 2; ++ph) {
        __syncthreads();                   // prev gather done before decode overwrites
        int w0 = ph * 64;
        int totA = decode64(wpA, w0, disA, s_nzA, s_off);
        int totB = decode64(wpB, w0, disB, s_nzB, s_off);
        int midB = (totB + 1) >> 1;
        if (half == 0) {
            for (int k = 0; k < totA; ++k) {
                uint2 p = s_nzA[k];
                accA = fmaf(__uint_as_float(p.y), PQ[(size_t)p.x * 128 + j], accA);
            }
        }
        int b0 = half ? midB : 0;
        int b1 = half ? totB : midB;
#pragma unroll 4
        for (int k = b0; k < b1; ++k) {
            uint2 p = s_nzB[k];
            accB = fmaf(__uint_as_float(p.y), PQ[(size_t)p.x * 128 + 64 + j], accB);
        }
    }
    s_res[tid] = accB;
    __syncthreads();
    if (tid < 64) {
        float add = disA[r] * accA + disB[r] * (s_res[tid] + s_res[tid + 64]);
        OUT[(size_t)r * OUTC + tid] += add;
    }
}

// ---------------------------------------------------------------------------
extern "C" void kernel_launch(void* const* d_in, const int* in_sizes, int n_in,
                              void* d_out, int out_size, void* d_ws, size_t ws_size,
                              hipStream_t stream) {
    const float* x     = (const float*)d_in[0];
    const float* adj   = (const float*)d_in[1];
    const float* adj2  = (const float*)d_in[2];
    const float* w_emb = (const float*)d_in[3];
    const float* b_emb = (const float*)d_in[4];
    const float* gamma = (const float*)d_in[5];
    const float* beta  = (const float*)d_in[6];
    const float* w_fin = (const float*)d_in[7];
    const float* b_fin = (const float*)d_in[8];
    float* out = (float*)d_out;

    if (ws_size < WS_NEED) return;   // needs ~44 MB scratch

    char* ws = (char*)d_ws;
    float* h    = (float*)(ws + OFF_H);
    float* z    = (float*)(ws + OFF_Z);
    float* pq   = (float*)(ws + OFF_PQ);
    u64*   bmp  = (u64*)  (ws + OFF_BMP);
    float* dis  = (float*)(ws + OFF_DIS);
    float* gsum = (float*)(ws + OFF_SUM);
    float* gssq = (float*)(ws + OFF_SSQ);

    // sparsify both adjacencies into bitmaps + row norms
    extract_bitmap<<<dim3(NR, 2), 256, 0, stream>>>(adj, adj2, bmp, dis);

    // h = relu(x @ w_embed^T + b)
    gemm_embed<<<dim3(NR / 64, HID / 64), 256, 0, stream>>>(x, w_emb, b_emb, h);

    // conv1: z = [A@h | A2@h]   float2 gather, 4 col-phases (2MB slice, L2-res)
    spmm_kernel<HID, 2, 4><<<NR, HID / 2, 0, stream>>>(bmp, dis, h, z);

    // BatchNorm over z
    zero_stats<<<4, 256, 0, stream>>>(gsum, gssq);
    bn_stats<<<dim3(8, 64), 256, 0, stream>>>(z, gsum, gssq);
    bn_apply<<<(NR * 2 * HID) / 256, 256, 0, stream>>>(z, gsum, gssq, gamma, beta);

    // PQ = z @ [W3a|W3b]^T  (the z2 contribution factored through w_fin)
    gemm_pq<<<NR / 32, 256, 0, stream>>>(z, w_fin, pq);

    // out = h@W1^T + z@W2^T + b   (K=768)
    gemm_final<<<NR / 32, 128, 0, stream>>>(h, z, w_fin, b_fin, out);

    // out += A@P + A2@Q   (width-128 gather over L2-resident PQ)
    spmm_pq<<<NR, 128, 0, stream>>>(bmp, dis, pq, out);
}

// Round 11
// 1492.264 us; speedup vs baseline: 1.0113x; 1.0113x over previous
//
#include <hip/hip_runtime.h>
#include <stdint.h>

typedef unsigned long long u64;

#define NR   8192
#define INC  512
#define HID  256
#define OUTC 64
#define NW   128          // 8192 / 64 bitmap words per row
#define BN_EPS 1e-5f
#define NZBUF 1152        // max nnz per decode window (worst ~550-1000; ample margin)

// ---------------- workspace layout ----------------
static constexpr size_t OFF_H    = 0;                               // [NR][HID]   f32  8 MB
static constexpr size_t OFF_Z    = OFF_H    + (size_t)NR*HID*4;     // [NR][2HID]  f32 16 MB
static constexpr size_t OFF_PQ   = OFF_Z    + (size_t)NR*2*HID*4;   // [NR][128]   f32  4 MB
static constexpr size_t OFF_BMP  = OFF_PQ   + (size_t)NR*128*4;     // [2][NR][NW] u64 16 MB
static constexpr size_t OFF_DIS  = OFF_BMP  + (size_t)2*NR*NW*8;    // [2][NR] f32
static constexpr size_t OFF_SUM  = OFF_DIS  + (size_t)2*NR*4;
static constexpr size_t OFF_SSQ  = OFF_SUM  + (size_t)2*HID*4;
static constexpr size_t WS_NEED  = OFF_SSQ  + (size_t)2*HID*4;      // ~44 MB

// ---------------------------------------------------------------------------
// 1. Bitmap extraction + row norm. grid (NR, 2); dis[r] = 1/sqrt(rownnz).
__global__ void extract_bitmap(const float* __restrict__ A, const float* __restrict__ A2,
                               u64* __restrict__ words, float* __restrict__ dis) {
    const int r    = blockIdx.x;
    const int mat  = blockIdx.y;
    const int tid  = threadIdx.x;
    const int lane = tid & 63;
    const int wv   = tid >> 6;             // 4 waves
    __shared__ int scnt;
    if (tid == 0) scnt = 0;
    __syncthreads();
    const float* rowp = (mat ? A2 : A) + (size_t)r * NR;
    u64* wout = words + ((size_t)mat * NR + r) * NW;
    int myc = 0;
    for (int w = wv; w < NW; w += 4) {
        float v = rowp[w * 64 + lane];     // 256B coalesced per wave
        u64 m = __ballot(v != 0.0f);
        if (lane == 0) {
            wout[w] = m;
            myc += __popcll(m);
        }
    }
    if (lane == 0) atomicAdd(&scnt, myc);
    __syncthreads();
    if (tid == 0) {
        int c = scnt;
        dis[mat * NR + r] = (c > 0) ? (float)(1.0 / sqrt((double)c)) : 0.0f;
    }
}

// ---------------------------------------------------------------------------
// 2. Embed GEMM: h = relu(x @ w_embed^T + b)   M=8192 K=512 N=256, fp32 VALU
__global__ void gemm_embed(const float* __restrict__ X, const float* __restrict__ W,
                           const float* __restrict__ B, float* __restrict__ H) {
    __shared__ __align__(16) float sA[16][68];
    __shared__ __align__(16) float sB[16][68];
    const int m0 = blockIdx.x * 64, n0 = blockIdx.y * 64;
    const int tid = threadIdx.x;
    const int tx = tid & 15, ty = tid >> 4;
    float acc[4][4] = {};
    for (int kt = 0; kt < INC; kt += 16) {
        for (int e = tid; e < 64 * 16; e += 256) {
            int row = e >> 4, k = e & 15;
            sA[k][row] = X[(size_t)(m0 + row) * INC + kt + k];
            sB[k][row] = W[(size_t)(n0 + row) * INC + kt + k];
        }
        __syncthreads();
#pragma unroll
        for (int k = 0; k < 16; ++k) {
            float4 av = *(const float4*)&sA[k][ty * 4];
            float4 bv = *(const float4*)&sB[k][tx * 4];
            float a[4] = {av.x, av.y, av.z, av.w};
            float b[4] = {bv.x, bv.y, bv.z, bv.w};
#pragma unroll
            for (int i = 0; i < 4; ++i)
#pragma unroll
                for (int j = 0; j < 4; ++j) acc[i][j] = fmaf(a[i], b[j], acc[i][j]);
        }
        __syncthreads();
    }
#pragma unroll
    for (int i = 0; i < 4; ++i)
#pragma unroll
        for (int j = 0; j < 4; ++j) {
            int m = m0 + ty * 4 + i, n = n0 + tx * 4 + j;
            H[(size_t)m * HID + n] = fmaxf(acc[i][j] + B[n], 0.0f);
        }
}

// ---------------------------------------------------------------------------
// 3. Phased SpMM-accumulate. ONE column-phase per LAUNCH so all resident
//    blocks gather from the same 2MB source slice (per-XCD L2-resident);
//    launch boundary = grid-wide phase sync (fixes block phase-drift that
//    spilled gathers to L3/HBM: 1.17GB FETCH @ 2.1TB/s in round 8).
//    Records store PRE-MULTIPLIED byte offsets (col*WSRC*4) + col dis value.
//    Row scaling (disA[r], disB[r]) is folded into BatchNorm downstream.
template <int WSRC, int VEC>
__device__ void spmm_phase(const u64* __restrict__ wp, int w0, int nw,
                           const float* __restrict__ disc, const char* __restrict__ sbase,
                           uint2* s_nz, int* s_off, float* acc) {
    const int tid = threadIdx.x;
    __syncthreads();                       // protect shared reuse across calls
    u64 m = 0;
    if (tid < nw) {
        m = wp[w0 + tid];
        s_off[tid] = __popcll(m);
    }
    __syncthreads();
    if (tid < 64) {                        // exclusive scan over <=64 word counts
        int cnt_i = (tid < nw) ? s_off[tid] : 0;
        int v = cnt_i;
#pragma unroll
        for (int d = 1; d < 64; d <<= 1) {
            int t = __shfl_up(v, d, 64);
            if (tid >= d) v += t;
        }
        if (tid < nw) s_off[tid] = v - cnt_i;
        if (tid == 63) s_off[64] = v;      // total
    }
    __syncthreads();
    const int total = s_off[64];
    if (tid < nw) {
        int o = s_off[tid];
        u64 mm = m;
        while (mm) {
            int b = __builtin_ctzll(mm);
            mm &= mm - 1;
            int c = (w0 + tid) * 64 + b;
            s_nz[o] = make_uint2((unsigned)(c * (WSRC * 4)), __float_as_uint(disc[c]));
            ++o;
        }
    }
    __syncthreads();
#pragma unroll 4
    for (int k = 0; k < total; ++k) {
        uint2 p = s_nz[k];                 // ds_read_b64 broadcast
        float val = __uint_as_float(p.y);
        const float* sp = (const float*)(sbase + p.x);
        if constexpr (VEC == 2) {
            float2 v = *(const float2*)sp;
            acc[0] = fmaf(val, v.x, acc[0]);
            acc[1] = fmaf(val, v.y, acc[1]);
        } else {
            float4 v = *(const float4*)sp;
            acc[0] = fmaf(val, v.x, acc[0]);
            acc[1] = fmaf(val, v.y, acc[1]);
            acc[2] = fmaf(val, v.z, acc[2]);
            acc[3] = fmaf(val, v.w, acc[3]);
        }
    }
}

template <int WSRC, int VEC, int NWP, bool FIRST>
__global__ __launch_bounds__(128, 8)   // pin VGPR<=64: keep 32 waves/CU
void spmm_phase_acc(const u64* __restrict__ bmp, const float* __restrict__ dis,
                    const float* __restrict__ src, float* __restrict__ dst, int w0) {
    const int r = blockIdx.x;
    const int j = threadIdx.x;             // blockDim.x == WSRC/VEC == 128
    __shared__ uint2 s_nz[NZBUF];
    __shared__ int s_off[65];
    float accA[VEC] = {}, accB[VEC] = {};
    const char* sbase = (const char*)src + (size_t)(VEC * 4) * j;
    spmm_phase<WSRC, VEC>(bmp + (size_t)r * NW,        w0, NWP, dis,      sbase, s_nz, s_off, accA);
    spmm_phase<WSRC, VEC>(bmp + (size_t)(NR + r) * NW, w0, NWP, dis + NR, sbase, s_nz, s_off, accB);
#pragma unroll
    for (int q = 0; q < VEC; ++q) {
        float* pa = &dst[(size_t)r * 2 * WSRC + VEC * j + q];
        float* pb = &dst[(size_t)r * 2 * WSRC + WSRC + VEC * j + q];
        if constexpr (FIRST) { *pa = accA[q];  *pb = accB[q]; }
        else                 { *pa += accA[q]; *pb += accB[q]; }
    }
}

// ---------------------------------------------------------------------------
// 4. BatchNorm over z (raw sums); folds the row scaling disA[r]/disB[r]:
//    true z = rowscale * zraw. Stats and normalization on scaled values.
__global__ void zero_stats(float* __restrict__ gsum, float* __restrict__ gssq) {
    int i = blockIdx.x * 256 + threadIdx.x;
    if (i < 2 * HID) gsum[i] = 0.0f;
    else if (i < 4 * HID) gssq[i - 2 * HID] = 0.0f;
}

__global__ void bn_stats(const float* __restrict__ Z, const float* __restrict__ dis,
                         float* __restrict__ gsum, float* __restrict__ gssq) {
    // grid (8, 64): 8 col-groups of 64 (groups 0-3 = A-half, 4-7 = B-half)
    const int tid = threadIdx.x;
    const int cl = tid & 63, rg = tid >> 6;
    const int c = blockIdx.x * 64 + cl;
    const int r0 = blockIdx.y * 128 + rg * 32;
    const float* drow = (blockIdx.x < 4) ? dis : dis + NR;  // block-uniform
    float s = 0.0f, s2 = 0.0f;
    for (int i = 0; i < 32; ++i) {
        float v = Z[(size_t)(r0 + i) * (2 * HID) + c] * drow[r0 + i];
        s += v;
        s2 += v * v;
    }
    __shared__ float red[2][4][64];
    red[0][rg][cl] = s;
    red[1][rg][cl] = s2;
    __syncthreads();
    if (tid < 64) {
        float t0 = red[0][0][tid] + red[0][1][tid] + red[0][2][tid] + red[0][3][tid];
        float t1 = red[1][0][tid] + red[1][1][tid] + red[1][2][tid] + red[1][3][tid];
        atomicAdd(&gsum[blockIdx.x * 64 + tid], t0);
        atomicAdd(&gssq[blockIdx.x * 64 + tid], t1);
    }
}

__global__ void bn_apply(float* __restrict__ Z, const float* __restrict__ dis,
                         const float* __restrict__ gsum, const float* __restrict__ gssq,
                         const float* __restrict__ gamma, const float* __restrict__ beta) {
    const size_t idx = (size_t)blockIdx.x * 256 + threadIdx.x;   // < NR*512
    const int c = (int)(idx & (2 * HID - 1));
    const int r = (int)(idx >> 9);
    const float sc = ((c < HID) ? dis : dis + NR)[r];
    const float inv = 1.0f / (float)NR;
    float mean = gsum[c] * inv;
    float var = fmaxf(gssq[c] * inv - mean * mean, 0.0f);
    float rs = rsqrtf(var + BN_EPS);
    Z[idx] = (Z[idx] * sc - mean) * rs * gamma[c] + beta[c];
}

// ---------------------------------------------------------------------------
// 5. PQ GEMM: PQ[r][0:64]=z[r].W3a^T, PQ[r][64:128]=z[r].W3b^T
//    (W3a = w_fin[:,768:1280], W3b = w_fin[:,1280:1792]).
__global__ void gemm_pq(const float* __restrict__ Z, const float* __restrict__ WF,
                        float* __restrict__ PQ) {
    __shared__ __align__(16) float sA[16][36];
    __shared__ __align__(16) float sB[16][132];
    const int m0 = blockIdx.x * 32;
    const int tid = threadIdx.x;
    const int tx = tid & 31, ty = tid >> 5;   // tx: 32x4 = 128 cols, ty: 8x4 = 32 rows
    float acc[4][4] = {};
    for (int kt = 0; kt < 2 * HID; kt += 16) {
        for (int e = tid; e < 32 * 16; e += 256) {
            int row = e >> 4, k = e & 15;
            sA[k][row] = Z[(size_t)(m0 + row) * (2 * HID) + kt + k];
        }
        for (int e = tid; e < 128 * 16; e += 256) {
            int n = e >> 4, k = e & 15;
            int col = (n < 64) ? (3 * HID + kt + k) : (5 * HID + kt + k);
            sB[k][n] = WF[(size_t)(n & 63) * (7 * HID) + col];
        }
        __syncthreads();
#pragma unroll
        for (int k = 0; k < 16; ++k) {
            float4 av = *(const float4*)&sA[k][ty * 4];
            float4 bv = *(const float4*)&sB[k][tx * 4];
            float a[4] = {av.x, av.y, av.z, av.w};
            float b[4] = {bv.x, bv.y, bv.z, bv.w};
#pragma unroll
            for (int i = 0; i < 4; ++i)
#pragma unroll
                for (int j = 0; j < 4; ++j) acc[i][j] = fmaf(a[i], b[j], acc[i][j]);
        }
        __syncthreads();
    }
#pragma unroll
    for (int i = 0; i < 4; ++i)
#pragma unroll
        for (int j = 0; j < 4; ++j) {
            int m = m0 + ty * 4 + i, n = tx * 4 + j;
            PQ[(size_t)m * 128 + n] = acc[i][j];
        }
}

// ---------------------------------------------------------------------------
// 6. Final GEMM (h,z parts; K=768): out = h@W1^T + z@W2^T + b. spmm_pq adds z2 part.
__global__ void gemm_final(const float* __restrict__ H, const float* __restrict__ Z,
                           const float* __restrict__ WF, const float* __restrict__ B,
                           float* __restrict__ OUT) {
    __shared__ __align__(16) float sA[16][36];
    __shared__ __align__(16) float sB[16][68];
    const int m0 = blockIdx.x * 32;
    const int tid = threadIdx.x;
    const int tx = tid & 15, ty = tid >> 4;   // tx: 16x4 = 64 cols, ty: 8x4 = 32 rows
    float acc[4][4] = {};
    for (int kt = 0; kt < 3 * HID; kt += 16) {
        const float* src;
        int stride, koff;
        if (kt < HID) { src = H; stride = HID;     koff = kt; }
        else          { src = Z; stride = 2 * HID; koff = kt - HID; }
        for (int e = tid; e < 32 * 16; e += 128) {
            int row = e >> 4, k = e & 15;
            sA[k][row] = src[(size_t)(m0 + row) * stride + koff + k];
        }
        for (int e = tid; e < 64 * 16; e += 128) {
            int row = e >> 4, k = e & 15;
            sB[k][row] = WF[(size_t)row * (7 * HID) + kt + k];   // row<64 = out ch
        }
        __syncthreads();
#pragma unroll
        for (int k = 0; k < 16; ++k) {
            float4 av = *(const float4*)&sA[k][ty * 4];
            float4 bv = *(const float4*)&sB[k][tx * 4];
            float a[4] = {av.x, av.y, av.z, av.w};
            float b[4] = {bv.x, bv.y, bv.z, bv.w};
#pragma unroll
            for (int i = 0; i < 4; ++i)
#pragma unroll
                for (int j = 0; j < 4; ++j) acc[i][j] = fmaf(a[i], b[j], acc[i][j]);
        }
        __syncthreads();
    }
#pragma unroll
    for (int i = 0; i < 4; ++i)
#pragma unroll
        for (int j = 0; j < 4; ++j) {
            int m = m0 + ty * 4 + i, n = tx * 4 + j;
            OUT[(size_t)m * OUTC + n] = acc[i][j] + B[n];
        }
}

// ---------------------------------------------------------------------------
// 7. conv2' SpMM (phased per LAUNCH, 64-word window -> 2MB PQ slice):
//    out[r][j] += disA[r]*sum_{c in A(r),win} disA[c]*P[c][j]
//               + disB[r]*sum_{c in A2(r),win} disB[c]*Q[c][j]
__device__ int decode64(const u64* __restrict__ wp, int w0,
                        const float* __restrict__ disc, uint2* s_nz, int* s_off) {
    const int tid = threadIdx.x;
    u64 m = 0;
    if (tid < 64) {
        m = wp[w0 + tid];
        s_off[tid] = __popcll(m);
    }
    __syncthreads();
    if (tid < 64) {
        int cnt_i = s_off[tid];
        int v = cnt_i;
#pragma unroll
        for (int d = 1; d < 64; d <<= 1) {
            int t = __shfl_up(v, d, 64);
            if (tid >= d) v += t;
        }
        s_off[tid] = v - cnt_i;
        if (tid == 63) s_off[64] = v;
    }
    __syncthreads();
    int total = s_off[64];
    if (tid < 64) {
        int o = s_off[tid];
        u64 mm = m;
        while (mm) {
            int b = __builtin_ctzll(mm);
            mm &= mm - 1;
            int c = (w0 + tid) * 64 + b;
            s_nz[o] = make_uint2((unsigned)(c * 512), __float_as_uint(disc[c]));  // byte off
            ++o;
        }
    }
    __syncthreads();
    return total;
}

__global__ __launch_bounds__(128, 8)
void spmm_pq(const u64* __restrict__ bmp, const float* __restrict__ dis,
             const float* __restrict__ PQ, float* __restrict__ OUT, int w0) {
    const int r = blockIdx.x;
    const int tid = threadIdx.x;
    const int j = tid & 63, half = tid >> 6;
    __shared__ uint2 s_nzA[128];
    __shared__ uint2 s_nzB[NZBUF];
    __shared__ int s_off[65];
    __shared__ float s_res[128];
    const float* disA = dis;
    const float* disB = dis + NR;
    float accA = 0.0f, accB = 0.0f;
    int totA = decode64(bmp + (size_t)r * NW,        w0, disA, s_nzA, s_off);
    __syncthreads();                       // s_off reuse between decodes
    int totB = decode64(bmp + (size_t)(NR + r) * NW, w0, disB, s_nzB, s_off);
    const char* base = (const char*)PQ + 4 * j;
    int midB = (totB + 1) >> 1;
    if (half == 0) {
        for (int k = 0; k < totA; ++k) {
            uint2 p = s_nzA[k];
            accA = fmaf(__uint_as_float(p.y), *(const float*)(base + p.x), accA);
        }
    }
    int b0 = half ? midB : 0;
    int b1 = half ? totB : midB;
#pragma unroll 4
    for (int k = b0; k < b1; ++k) {
        uint2 p = s_nzB[k];
        accB = fmaf(__uint_as_float(p.y), *(const float*)(base + 256 + p.x), accB);
    }
    s_res[tid] = accB;
    __syncthreads();
    if (tid < 64) {
        float add = disA[r] * accA + disB[r] * (s_res[tid] + s_res[tid + 64]);
        OUT[(size_t)r * OUTC + tid] += add;
    }
}

// ---------------------------------------------------------------------------
extern "C" void kernel_launch(void* const* d_in, const int* in_sizes, int n_in,
                              void* d_out, int out_size, void* d_ws, size_t ws_size,
                              hipStream_t stream) {
    const float* x     = (const float*)d_in[0];
    const float* adj   = (const float*)d_in[1];
    const float* adj2  = (const float*)d_in[2];
    const float* w_emb = (const float*)d_in[3];
    const float* b_emb = (const float*)d_in[4];
    const float* gamma = (const float*)d_in[5];
    const float* beta  = (const float*)d_in[6];
    const float* w_fin = (const float*)d_in[7];
    const float* b_fin = (const float*)d_in[8];
    float* out = (float*)d_out;

    if (ws_size < WS_NEED) return;   // needs ~44 MB scratch

    char* ws = (char*)d_ws;
    float* h    = (float*)(ws + OFF_H);
    float* z    = (float*)(ws + OFF_Z);
    float* pq   = (float*)(ws + OFF_PQ);
    u64*   bmp  = (u64*)  (ws + OFF_BMP);
    float* dis  = (float*)(ws + OFF_DIS);
    float* gsum = (float*)(ws + OFF_SUM);
    float* gssq = (float*)(ws + OFF_SSQ);

    // sparsify both adjacencies into bitmaps + row norms
    extract_bitmap<<<dim3(NR, 2), 256, 0, stream>>>(adj, adj2, bmp, dis);

    // h = relu(x @ w_embed^T + b)
    gemm_embed<<<dim3(NR / 64, HID / 64), 256, 0, stream>>>(x, w_emb, b_emb, h);

    // conv1 raw sums: z = [sumA(h) | sumA2(h)], one 2MB col-slice per LAUNCH
    spmm_phase_acc<HID, 2, 32, true ><<<NR, 128, 0, stream>>>(bmp, dis, h, z, 0);
    spmm_phase_acc<HID, 2, 32, false><<<NR, 128, 0, stream>>>(bmp, dis, h, z, 32);
    spmm_phase_acc<HID, 2, 32, false><<<NR, 128, 0, stream>>>(bmp, dis, h, z, 64);
    spmm_phase_acc<HID, 2, 32, false><<<NR, 128, 0, stream>>>(bmp, dis, h, z, 96);

    // BatchNorm over z (folds disA[r]/disB[r] row scaling)
    zero_stats<<<4, 256, 0, stream>>>(gsum, gssq);
    bn_stats<<<dim3(8, 64), 256, 0, stream>>>(z, dis, gsum, gssq);
    bn_apply<<<(NR * 2 * HID) / 256, 256, 0, stream>>>(z, dis, gsum, gssq, gamma, beta);

    // PQ = z @ [W3a|W3b]^T  (the z2 contribution factored through w_fin)
    gemm_pq<<<NR / 32, 256, 0, stream>>>(z, w_fin, pq);

    // out = h@W1^T + z@W2^T + b   (K=768)
    gemm_final<<<NR / 32, 128, 0, stream>>>(h, z, w_fin, b_fin, out);

    // out += A@P + A2@Q   (2MB PQ slice per LAUNCH)
    spmm_pq<<<NR, 128, 0, stream>>>(bmp, dis, pq, out, 0);
    spmm_pq<<<NR, 128, 0, stream>>>(bmp, dis, pq, out, 64);
}